// Round 3
// baseline (1494.031 us; speedup 1.0000x reference)
//
#include <hip/hip_runtime.h>
#include <math.h>

#define NBLK 512
#define THR  256
#define EPSF 1e-8f

__device__ __forceinline__ float sigmoidf_(float x) { return 1.0f / (1.0f + expf(-x)); }
__device__ __forceinline__ float softplusf_(float x) { return fmaxf(x, 0.0f) + log1pf(expf(-fabsf(x))); }
__device__ __forceinline__ float4 ld4(const float* p) { return *(const float4*)p; }

struct Args {
    const float *in_data, *memory, *h_prev, *c_prev, *prev_reads, *prev_weights;
    const float *W_ih, *b_ih, *W_hh, *b_hh, *W_out, *b_out;
    const float *Wk, *bk, *Wbeta, *bbeta, *Wg, *bg, *Ws3, *bs3, *Wgam, *bgam, *We, *be, *Wa, *ba;
    float *gates, *cbuf, *hbuf, *Chead, *keys, *knorm, *betaA, *gA, *gammaA, *sA, *eA, *aA;
    float *sims, *wbuf, *outacc, *rbuf, *out;
    int *bar_g, *bar_r, *bar_s;
};

union SMem {
    struct { float wg[4096]; float red[256]; } w;
    struct { float A[32 * 65]; float W[32 * 33]; } g;
    struct { float part[16][64]; } s;
    struct { float sk[64]; float s3[3]; } h;
};

// ---- two-level grid barrier: 32 groups x 16 blocks, monotone counters ----
__device__ __forceinline__ void gridbar(const Args& a, int k) {
    __syncthreads();
    if (threadIdx.x == 0) {
        int g = blockIdx.x & 31;
        bool done = false;
        if (__hip_atomic_fetch_add(&a.bar_g[g << 5], 1, __ATOMIC_ACQ_REL, __HIP_MEMORY_SCOPE_AGENT) == k * 16 - 1) {
            if (__hip_atomic_fetch_add(a.bar_r, 1, __ATOMIC_ACQ_REL, __HIP_MEMORY_SCOPE_AGENT) == k * 32 - 1) {
                __hip_atomic_store(a.bar_s, k, __ATOMIC_RELEASE, __HIP_MEMORY_SCOPE_AGENT);
                done = true;
            }
        }
        if (!done) {
            while (__hip_atomic_load(a.bar_s, __ATOMIC_ACQUIRE, __HIP_MEMORY_SCOPE_AGENT) < k)
                __builtin_amdgcn_s_sleep(1);
        }
    }
    __syncthreads();
}

// ---- generic small GEMM phase: C[128,Ncols] = A[128,K] @ W[Ncols,K]^T ----
// tile = 64 batch x 32 outs, full K per tile (no atomics). mode selects gathers.
__device__ float4 gatherA(const Args& a, int mode, int row, int k) {
    if (mode == 0) {
        if (k < 256)      return ld4(a.in_data + row * 256 + k);
        else if (k < 512) { int kk = k - 256; return ld4(a.prev_reads + (size_t)((kk >> 6) * 128 + row) * 64 + (kk & 63)); }
        else              return ld4(a.h_prev + row * 512 + (k - 512));
    } else if (mode == 1) {
        return ld4(a.cbuf + row * 512 + k);
    } else {
        if (k < 512) return ld4(a.hbuf + row * 512 + k);
        int kk = k - 512;
        return ld4(a.rbuf + (size_t)((kk >> 6) * 128 + row) * 64 + (kk & 63));
    }
}

__device__ float4 gatherW(const Args& a, int mode, int o, int k) {
    if (mode == 0) {
        if (k < 512) return ld4(a.W_ih + (size_t)o * 512 + k);
        return ld4(a.W_hh + (size_t)o * 512 + (k - 512));
    } else if (mode == 2) {
        return ld4(a.W_out + (size_t)o * 768 + k);
    } else {
        if (o >= 1584) return make_float4(0.f, 0.f, 0.f, 0.f);
        int i = o / 198, q = o - i * 198;
        if (q < 64)       return ld4(a.Wk + (size_t)((i << 6) + q) * 512 + k);
        else if (q == 64) return ld4(a.Wbeta + (size_t)i * 512 + k);
        else if (q == 65) return ld4(a.Wg + (size_t)i * 512 + k);
        else if (q <= 68) return ld4(a.Ws3 + (size_t)(i * 3 + q - 66) * 512 + k);
        else if (q == 69) return ld4(a.Wgam + (size_t)i * 512 + k);
        else if (q < 134) return ld4(a.We + (size_t)((i << 6) + q - 70) * 512 + k);
        else              return ld4(a.Wa + (size_t)((i << 6) + q - 134) * 512 + k);
    }
}

__device__ void gemm_phase(const Args& a, SMem& sm, int mode, int K, int Ncols, float* C) {
    int ntiles = 2 * (Ncols >> 5);
    int t = threadIdx.x;
    for (int tile = blockIdx.x; tile < ntiles; tile += NBLK) {
        int rb = (tile & 1) * 64;
        int o0 = (tile >> 1) * 32;
        float acc[4][2] = {{0.f, 0.f}, {0.f, 0.f}, {0.f, 0.f}, {0.f, 0.f}};
        for (int k0 = 0; k0 < K; k0 += 32) {
            __syncthreads();
#pragma unroll
            for (int i = 0; i < 2; ++i) {
                int idx = t + THR * i;
                int row = idx >> 3, c4 = (idx & 7) * 4;
                float4 v = gatherA(a, mode, rb + row, k0 + c4);
                sm.g.A[(c4 + 0) * 65 + row] = v.x;
                sm.g.A[(c4 + 1) * 65 + row] = v.y;
                sm.g.A[(c4 + 2) * 65 + row] = v.z;
                sm.g.A[(c4 + 3) * 65 + row] = v.w;
            }
            {
                int o = t >> 3, c4 = (t & 7) * 4;
                float4 v = gatherW(a, mode, o0 + o, k0 + c4);
                sm.g.W[(c4 + 0) * 33 + o] = v.x;
                sm.g.W[(c4 + 1) * 33 + o] = v.y;
                sm.g.W[(c4 + 2) * 33 + o] = v.z;
                sm.g.W[(c4 + 3) * 33 + o] = v.w;
            }
            __syncthreads();
            int ob = (t & 7) * 4, bb = (t >> 3) * 2;
#pragma unroll
            for (int kk = 0; kk < 32; ++kk) {
                const float* wp = &sm.g.W[kk * 33 + ob];
                const float* ap = &sm.g.A[kk * 65 + bb];
                float a0 = ap[0], a1 = ap[1];
                float w0 = wp[0], w1 = wp[1], w2 = wp[2], w3 = wp[3];
                acc[0][0] = fmaf(w0, a0, acc[0][0]); acc[0][1] = fmaf(w0, a1, acc[0][1]);
                acc[1][0] = fmaf(w1, a0, acc[1][0]); acc[1][1] = fmaf(w1, a1, acc[1][1]);
                acc[2][0] = fmaf(w2, a0, acc[2][0]); acc[2][1] = fmaf(w2, a1, acc[2][1]);
                acc[3][0] = fmaf(w3, a0, acc[3][0]); acc[3][1] = fmaf(w3, a1, acc[3][1]);
            }
        }
        int ob = (t & 7) * 4, bb = (t >> 3) * 2;
#pragma unroll
        for (int i = 0; i < 4; ++i)
#pragma unroll
            for (int j = 0; j < 2; ++j)
                C[(size_t)(rb + bb + j) * Ncols + o0 + ob + i] = acc[i][j];
    }
}

__device__ float biasHead(const Args& a, int i, int q) {
    if (q < 64)  return a.bk[(i << 6) + q];
    if (q == 64) return a.bbeta[i];
    if (q == 65) return a.bg[i];
    if (q <= 68) return a.bs3[i * 3 + q - 66];
    if (q == 69) return a.bgam[i];
    if (q < 134) return a.be[(i << 6) + q - 70];
    return a.ba[(i << 6) + q - 134];
}

// ---- read-only memory sweep; reconstruct states in registers ----
__device__ void sweep_phase(const Args& a, SMem& sm, int napply, int nsims, int sh0, int sh1,
                            int read_state, int read_head, int read_idx) {
    int t = threadIdx.x, lane = t & 15, grp = t >> 4;
    int base = blockIdx.x * 1024;   // 1024 rows/block, 4 blocks per b
    int b = base >> 12;
    int m4 = lane * 4;
    float4 e1 = ld4(a.eA + (size_t)(1 * 128 + b) * 64 + m4);
    float4 a1 = ld4(a.aA + (size_t)(1 * 128 + b) * 64 + m4);
    float4 e3 = ld4(a.eA + (size_t)(3 * 128 + b) * 64 + m4);
    float4 a3 = ld4(a.aA + (size_t)(3 * 128 + b) * 64 + m4);
    float4 e5 = ld4(a.eA + (size_t)(5 * 128 + b) * 64 + m4);
    float4 a5 = ld4(a.aA + (size_t)(5 * 128 + b) * 64 + m4);
    float4 k0v = make_float4(0.f, 0.f, 0.f, 0.f), k1v = k0v;
    float kn0 = 0.f, kn1 = 0.f;
    if (nsims > 0) { k0v = ld4(a.keys + (size_t)(sh0 * 128 + b) * 64 + m4); kn0 = a.knorm[sh0 * 128 + b]; }
    if (nsims > 1) { k1v = ld4(a.keys + (size_t)(sh1 * 128 + b) * 64 + m4); kn1 = a.knorm[sh1 * 128 + b]; }
    const float* w1p = a.wbuf + (size_t)1 * 128 * 4096;
    const float* w3p = a.wbuf + (size_t)3 * 128 * 4096;
    const float* w5p = a.wbuf + (size_t)5 * 128 * 4096;
    const float* wrp = (read_head >= 0) ? a.wbuf + (size_t)read_head * 128 * 4096 : nullptr;
    float* sim0 = a.sims + (size_t)sh0 * 128 * 4096;
    float* sim1 = a.sims + (size_t)sh1 * 128 * 4096;
    float4 racc = make_float4(0.f, 0.f, 0.f, 0.f);

    auto proc = [&](float4 m, int row) {
        float4 mr = m;
        if (napply >= 1) {
            float w = w1p[row];
            m.x = m.x * (1.f - w * e1.x) + w * a1.x;
            m.y = m.y * (1.f - w * e1.y) + w * a1.y;
            m.z = m.z * (1.f - w * e1.z) + w * a1.z;
            m.w = m.w * (1.f - w * e1.w) + w * a1.w;
            if (read_state == 1) mr = m;
        }
        if (napply >= 2) {
            float w = w3p[row];
            m.x = m.x * (1.f - w * e3.x) + w * a3.x;
            m.y = m.y * (1.f - w * e3.y) + w * a3.y;
            m.z = m.z * (1.f - w * e3.z) + w * a3.z;
            m.w = m.w * (1.f - w * e3.w) + w * a3.w;
            if (read_state == 2) mr = m;
        }
        if (napply >= 3) {
            float w = w5p[row];
            m.x = m.x * (1.f - w * e5.x) + w * a5.x;
            m.y = m.y * (1.f - w * e5.y) + w * a5.y;
            m.z = m.z * (1.f - w * e5.z) + w * a5.z;
            m.w = m.w * (1.f - w * e5.w) + w * a5.w;
            if (read_state == 3) mr = m;
        }
        if (read_head >= 0) {
            float w = wrp[row];
            racc.x = fmaf(w, mr.x, racc.x);
            racc.y = fmaf(w, mr.y, racc.y);
            racc.z = fmaf(w, mr.z, racc.z);
            racc.w = fmaf(w, mr.w, racc.w);
        }
        if (nsims > 0) {
            float d0 = m.x * k0v.x + m.y * k0v.y + m.z * k0v.z + m.w * k0v.w;
            float nn = m.x * m.x + m.y * m.y + m.z * m.z + m.w * m.w;
            float d1 = 0.f;
            if (nsims > 1) d1 = m.x * k1v.x + m.y * k1v.y + m.z * k1v.z + m.w * k1v.w;
#pragma unroll
            for (int off = 8; off >= 1; off >>= 1) {
                d0 += __shfl_xor(d0, off, 16);
                nn += __shfl_xor(nn, off, 16);
                if (nsims > 1) d1 += __shfl_xor(d1, off, 16);
            }
            if (lane == 0) {
                float nm = sqrtf(nn);
                sim0[row] = d0 / (nm * kn0 + EPSF);
                if (nsims > 1) sim1[row] = d1 / (nm * kn1 + EPSF);
            }
        }
    };

    for (int it = 0; it < 64; it += 4) {
        int r0 = base + it * 16 + grp;
        const float* mp = a.memory + (size_t)r0 * 64 + m4;
        float4 m0 = ld4(mp);
        float4 m1 = ld4(mp + 16 * 64);
        float4 m2 = ld4(mp + 32 * 64);
        float4 m3 = ld4(mp + 48 * 64);
        proc(m0, r0); proc(m1, r0 + 16); proc(m2, r0 + 32); proc(m3, r0 + 48);
    }
    if (read_head >= 0) {
        *(float4*)(&sm.s.part[grp][m4]) = racc;
        __syncthreads();
        if (t < 64) {
            float s = 0.f;
#pragma unroll
            for (int g2 = 0; g2 < 16; ++g2) s += sm.s.part[g2][t];
            atomicAdd(&a.rbuf[(size_t)(read_idx * 128 + b) * 64 + t], s);
        }
    }
}

// ---- softmax(beta*sim) -> interpolate -> shift -> sharpen -> normalize ----
__device__ void weights_phase(const Args& a, SMem& sm, int head0, int nheads) {
    int pair = blockIdx.x;
    if (pair >= nheads * 128) return;
    int h = head0 + (pair >> 7), b = pair & 127;
    int hb = h * 128 + b;
    float beta = a.betaA[hb], g = a.gA[hb], gamma = a.gammaA[hb];
    float s0 = a.sA[hb * 3 + 0], s1 = a.sA[hb * 3 + 1], s2 = a.sA[hb * 3 + 2];
    const float* sim = a.sims + (size_t)hb * 4096;
    const float* pw = a.prev_weights + (size_t)hb * 4096;
    float* wout = a.wbuf + (size_t)hb * 4096;
    int t = threadIdx.x;
    float tv[16];
    float lmax = -3.4e38f;
#pragma unroll
    for (int j = 0; j < 16; ++j) {
        float x = beta * sim[t + 256 * j];
        tv[j] = x;
        lmax = fmaxf(lmax, x);
    }
    sm.w.red[t] = lmax; __syncthreads();
    for (int s = 128; s > 0; s >>= 1) { if (t < s) sm.w.red[t] = fmaxf(sm.w.red[t], sm.w.red[t + s]); __syncthreads(); }
    float Mx = sm.w.red[0]; __syncthreads();
    float lsum = 0.f;
#pragma unroll
    for (int j = 0; j < 16; ++j) { float ex = expf(tv[j] - Mx); tv[j] = ex; lsum += ex; }
    sm.w.red[t] = lsum; __syncthreads();
    for (int s = 128; s > 0; s >>= 1) { if (t < s) sm.w.red[t] += sm.w.red[t + s]; __syncthreads(); }
    float invS = 1.f / sm.w.red[0]; __syncthreads();
#pragma unroll
    for (int j = 0; j < 16; ++j) {
        int n = t + 256 * j;
        sm.w.wg[n] = g * tv[j] * invS + (1.f - g) * pw[n];
    }
    __syncthreads();
    float lsum2 = 0.f;
#pragma unroll
    for (int j = 0; j < 16; ++j) {
        int n = t + 256 * j;
        float wsft = s0 * sm.w.wg[(n + 1) & 4095] + s1 * sm.w.wg[n] + s2 * sm.w.wg[(n - 1) & 4095];
        float wp = exp2f(gamma * log2f(wsft));   // wsft >= 0; 0 -> 0 correctly
        tv[j] = wp;
        lsum2 += wp;
    }
    sm.w.red[t] = lsum2; __syncthreads();
    for (int s = 128; s > 0; s >>= 1) { if (t < s) sm.w.red[t] += sm.w.red[t + s]; __syncthreads(); }
    float inv2 = 1.f / (sm.w.red[0] + EPSF);
#pragma unroll
    for (int j = 0; j < 16; ++j) wout[t + 256 * j] = tv[j] * inv2;
}

// ------------------------------------------------------------------
__global__ __launch_bounds__(THR, 2) void ntm_fused(Args a) {
    __shared__ SMem sm;
    int t = threadIdx.x;

    // P0: gates = [x|reads|h] @ [W_ih|W_hh]^T
    gemm_phase(a, sm, 0, 1024, 2048, a.gates);
    gridbar(a, 1);
    // P1: LSTM pointwise
    if (blockIdx.x < 256) {
        int idx = blockIdx.x * THR + t;
        int j = idx & 511;
        const float* gr = a.gates + (size_t)(idx >> 9) * 2048;
        float gi = gr[j]        + a.b_ih[j]        + a.b_hh[j];
        float gf = gr[512 + j]  + a.b_ih[512 + j]  + a.b_hh[512 + j];
        float gg = gr[1024 + j] + a.b_ih[1024 + j] + a.b_hh[1024 + j];
        float go = gr[1536 + j] + a.b_ih[1536 + j] + a.b_hh[1536 + j];
        float cc = sigmoidf_(gf) * a.c_prev[idx] + sigmoidf_(gi) * tanhf(gg);
        a.cbuf[idx] = cc;
        a.hbuf[idx] = sigmoidf_(go) * tanhf(cc);
    }
    gridbar(a, 2);
    // P2: head-param GEMM (weights gathered from original arrays)
    gemm_phase(a, sm, 1, 512, 1600, a.Chead);
    gridbar(a, 3);
    // P3: head activations (2 items per block)
    for (int ii = 0; ii < 2; ++ii) {
        int item = blockIdx.x * 2 + ii;
        int i = item >> 7, b = item & 127;
        float val = 0.f;
        if (t < 198) val = a.Chead[(size_t)b * 1600 + i * 198 + t] + biasHead(a, i, t);
        if (t < 64) { a.keys[(size_t)(i * 128 + b) * 64 + t] = val; sm.h.sk[t] = val * val; }
        if (t >= 66 && t <= 68) sm.h.s3[t - 66] = val;
        __syncthreads();
        if (t == 0) {
            float s = 0.f;
            for (int m2 = 0; m2 < 64; ++m2) s += sm.h.sk[m2];
            a.knorm[i * 128 + b] = sqrtf(s);
        }
        if (t == 64) a.betaA[i * 128 + b] = softplusf_(val);
        if (t == 65) a.gA[i * 128 + b] = sigmoidf_(val);
        if (t == 69) a.gammaA[i * 128 + b] = 1.f + softplusf_(val);
        if (t == 66) {
            float mx = fmaxf(sm.h.s3[0], fmaxf(sm.h.s3[1], sm.h.s3[2]));
            float e0 = expf(sm.h.s3[0] - mx), e1 = expf(sm.h.s3[1] - mx), e2 = expf(sm.h.s3[2] - mx);
            float inv = 1.f / (e0 + e1 + e2);
            a.sA[(i * 128 + b) * 3 + 0] = e0 * inv;
            a.sA[(i * 128 + b) * 3 + 1] = e1 * inv;
            a.sA[(i * 128 + b) * 3 + 2] = e2 * inv;
        }
        if (t >= 70 && t < 134)  a.eA[(size_t)(i * 128 + b) * 64 + (t - 70)] = sigmoidf_(val);
        if (t >= 134 && t < 198) a.aA[(size_t)(i * 128 + b) * 64 + (t - 134)] = tanhf(val);
        __syncthreads();
    }
    gridbar(a, 4);
    // sweeps + weight chains
    sweep_phase(a, sm, 0, 2, 0, 1, -1, -1, 0);   gridbar(a, 5);
    weights_phase(a, sm, 0, 2);                  gridbar(a, 6);
    sweep_phase(a, sm, 1, 2, 2, 3, 0, 0, 0);     gridbar(a, 7);
    weights_phase(a, sm, 2, 2);                  gridbar(a, 8);
    sweep_phase(a, sm, 2, 2, 4, 5, 1, 2, 1);     gridbar(a, 9);
    weights_phase(a, sm, 4, 2);                  gridbar(a, 10);
    sweep_phase(a, sm, 3, 1, 6, 6, 2, 4, 2);     gridbar(a, 11);
    weights_phase(a, sm, 6, 1);                  gridbar(a, 12);
    sweep_phase(a, sm, 3, 0, 0, 0, 3, 6, 3);     gridbar(a, 13);
    // P13: output GEMM over [h | r0 r2 r4 r6]
    gemm_phase(a, sm, 2, 768, 256, a.outacc);
    gridbar(a, 14);
    // P14: sigmoid epilogue
    if (blockIdx.x < 128) {
        int idx = blockIdx.x * THR + t;
        a.out[idx] = sigmoidf_(a.outacc[idx] + a.b_out[idx & 255]);
    }
}

// ------------------------------------------------------------------
extern "C" void kernel_launch(void* const* d_in, const int* in_sizes, int n_in,
                              void* d_out, int out_size, void* d_ws, size_t ws_size,
                              hipStream_t stream) {
    Args a;
    a.in_data      = (const float*)d_in[0];
    a.memory       = (const float*)d_in[1];
    a.h_prev       = (const float*)d_in[2];
    a.c_prev       = (const float*)d_in[3];
    a.prev_reads   = (const float*)d_in[4];
    a.prev_weights = (const float*)d_in[5];
    a.W_ih  = (const float*)d_in[6];
    a.b_ih  = (const float*)d_in[7];
    a.W_hh  = (const float*)d_in[8];
    a.b_hh  = (const float*)d_in[9];
    a.W_out = (const float*)d_in[10];
    a.b_out = (const float*)d_in[11];
    a.Wk    = (const float*)d_in[12];
    a.bk    = (const float*)d_in[13];
    a.Wbeta = (const float*)d_in[14];
    a.bbeta = (const float*)d_in[15];
    a.Wg    = (const float*)d_in[16];
    a.bg    = (const float*)d_in[17];
    a.Ws3   = (const float*)d_in[18];
    a.bs3   = (const float*)d_in[19];
    a.Wgam  = (const float*)d_in[20];
    a.bgam  = (const float*)d_in[21];
    a.We    = (const float*)d_in[22];
    a.be    = (const float*)d_in[23];
    a.Wa    = (const float*)d_in[24];
    a.ba    = (const float*)d_in[25];

    float* ws = (float*)d_ws;
    // zeroed control region: barrier vars (2048 ints) + rbuf (32768 floats)
    a.bar_g = (int*)ws;            // 32 groups, stride 32 ints
    a.bar_r = (int*)ws + 1024;
    a.bar_s = (int*)ws + 1088;
    a.rbuf  = ws + 2048;           // [4,128,64]
    size_t off = 2048 + 32768;
    a.gates  = ws + off; off += 262144;   // [128,2048]
    a.cbuf   = ws + off; off += 65536;
    a.hbuf   = ws + off; off += 65536;
    a.Chead  = ws + off; off += 204800;   // [128,1600]
    a.keys   = ws + off; off += 65536;    // [8,128,64]
    a.knorm  = ws + off; off += 1024;
    a.betaA  = ws + off; off += 1024;
    a.gA     = ws + off; off += 1024;
    a.gammaA = ws + off; off += 1024;
    a.sA     = ws + off; off += 3072;
    a.eA     = ws + off; off += 65536;
    a.aA     = ws + off; off += 65536;
    a.sims   = ws + off; off += 4194304;  // [8,128,4096]
    a.wbuf   = ws + off; off += 4194304;  // [8,128,4096]
    a.outacc = ws + off; off += 32768;    // [128,256]
    a.out    = (float*)d_out;

    hipMemsetAsync(d_ws, 0, (2048 + 32768) * sizeof(float), stream);
    ntm_fused<<<NBLK, THR, 0, stream>>>(a);

    (void)in_sizes; (void)n_in; (void)out_size; (void)ws_size;
}

// Round 4
// 763.271 us; speedup vs baseline: 1.9574x; 1.9574x over previous
//
#include <hip/hip_runtime.h>
#include <math.h>

#define NBLK 512
#define THR  256
#define EPSF 1e-8f

__device__ __forceinline__ float sigmoidf_(float x) { return 1.0f / (1.0f + expf(-x)); }
__device__ __forceinline__ float softplusf_(float x) { return fmaxf(x, 0.0f) + log1pf(expf(-fabsf(x))); }
__device__ __forceinline__ float4 ld4(const float* p) { return *(const float4*)p; }

struct Args {
    const float *in_data, *memory, *h_prev, *c_prev, *prev_reads, *prev_weights;
    const float *W_ih, *b_ih, *W_hh, *b_hh, *W_out, *b_out;
    const float *Wk, *bk, *Wbeta, *bbeta, *Wg, *bg, *Ws3, *bs3, *Wgam, *bgam, *We, *be, *Wa, *ba;
    float *gates, *cbuf, *hbuf, *Chead, *keys, *knorm, *betaA, *gA, *gammaA, *sA, *eA, *aA;
    float *sims, *wbuf, *rbuf, *out;
    int *bar_g, *bar_r, *bar_s;
};

union SMem {
    struct { float wg[4096]; float red[256]; } w;
    struct { float A[32 * 65]; float W[32 * 33]; } g;
    struct { float part[16][64]; } s;
    struct { float sk[64]; float s3[3]; } h;
};

// ---- two-level grid barrier: RELAXED spins (no per-poll cache inv!) ----
// one RELEASE fence at arrival (L2 writeback), one ACQUIRE fence at exit.
__device__ __forceinline__ void gridbar(const Args& a, int k) {
    __syncthreads();
    if (threadIdx.x == 0) {
        __builtin_amdgcn_fence(__ATOMIC_RELEASE, "agent");
        int g = blockIdx.x & 31;
        bool last = false;
        if (__hip_atomic_fetch_add(&a.bar_g[g << 5], 1, __ATOMIC_RELAXED, __HIP_MEMORY_SCOPE_AGENT) == k * 16 - 1) {
            if (__hip_atomic_fetch_add(a.bar_r, 1, __ATOMIC_RELAXED, __HIP_MEMORY_SCOPE_AGENT) == k * 32 - 1) {
                __hip_atomic_store(a.bar_s, k, __ATOMIC_RELAXED, __HIP_MEMORY_SCOPE_AGENT);
                last = true;
            }
        }
        if (!last) {
            while (__hip_atomic_load(a.bar_s, __ATOMIC_RELAXED, __HIP_MEMORY_SCOPE_AGENT) < k)
                __builtin_amdgcn_s_sleep(2);
        }
        __builtin_amdgcn_fence(__ATOMIC_ACQUIRE, "agent");
    }
    __syncthreads();
}

// ---- generic small GEMM phase: C[128,Ncols] = A[128,K] @ W[Ncols,K]^T ----
__device__ float4 gatherA(const Args& a, int mode, int row, int k) {
    if (mode == 0) {
        if (k < 256)      return ld4(a.in_data + row * 256 + k);
        else if (k < 512) { int kk = k - 256; return ld4(a.prev_reads + (size_t)((kk >> 6) * 128 + row) * 64 + (kk & 63)); }
        else              return ld4(a.h_prev + row * 512 + (k - 512));
    } else if (mode == 1) {
        return ld4(a.cbuf + row * 512 + k);
    } else {
        if (k < 512) return ld4(a.hbuf + row * 512 + k);
        int kk = k - 512;
        return ld4(a.rbuf + (size_t)((kk >> 6) * 128 + row) * 64 + (kk & 63));
    }
}

__device__ float4 gatherW(const Args& a, int mode, int o, int k) {
    if (mode == 0) {
        if (k < 512) return ld4(a.W_ih + (size_t)o * 512 + k);
        return ld4(a.W_hh + (size_t)o * 512 + (k - 512));
    } else if (mode == 2) {
        return ld4(a.W_out + (size_t)o * 768 + k);
    } else {
        if (o >= 1584) return make_float4(0.f, 0.f, 0.f, 0.f);
        int i = o / 198, q = o - i * 198;
        if (q < 64)       return ld4(a.Wk + (size_t)((i << 6) + q) * 512 + k);
        else if (q == 64) return ld4(a.Wbeta + (size_t)i * 512 + k);
        else if (q == 65) return ld4(a.Wg + (size_t)i * 512 + k);
        else if (q <= 68) return ld4(a.Ws3 + (size_t)(i * 3 + q - 66) * 512 + k);
        else if (q == 69) return ld4(a.Wgam + (size_t)i * 512 + k);
        else if (q < 134) return ld4(a.We + (size_t)((i << 6) + q - 70) * 512 + k);
        else              return ld4(a.Wa + (size_t)((i << 6) + q - 134) * 512 + k);
    }
}

__device__ void gemm_phase(const Args& a, SMem& sm, int mode, int K, int Ncols, float* C) {
    int ntiles = 2 * (Ncols >> 5);
    int t = threadIdx.x;
    for (int tile = blockIdx.x; tile < ntiles; tile += NBLK) {
        int rb = (tile & 1) * 64;
        int o0 = (tile >> 1) * 32;
        float acc[4][2] = {{0.f, 0.f}, {0.f, 0.f}, {0.f, 0.f}, {0.f, 0.f}};
        for (int k0 = 0; k0 < K; k0 += 32) {
            __syncthreads();
#pragma unroll
            for (int i = 0; i < 2; ++i) {
                int idx = t + THR * i;
                int row = idx >> 3, c4 = (idx & 7) * 4;
                float4 v = gatherA(a, mode, rb + row, k0 + c4);
                sm.g.A[(c4 + 0) * 65 + row] = v.x;
                sm.g.A[(c4 + 1) * 65 + row] = v.y;
                sm.g.A[(c4 + 2) * 65 + row] = v.z;
                sm.g.A[(c4 + 3) * 65 + row] = v.w;
            }
            {
                int o = t >> 3, c4 = (t & 7) * 4;
                float4 v = gatherW(a, mode, o0 + o, k0 + c4);
                sm.g.W[(c4 + 0) * 33 + o] = v.x;
                sm.g.W[(c4 + 1) * 33 + o] = v.y;
                sm.g.W[(c4 + 2) * 33 + o] = v.z;
                sm.g.W[(c4 + 3) * 33 + o] = v.w;
            }
            __syncthreads();
            int ob = (t & 7) * 4, bb = (t >> 3) * 2;
#pragma unroll
            for (int kk = 0; kk < 32; ++kk) {
                const float* wp = &sm.g.W[kk * 33 + ob];
                const float* ap = &sm.g.A[kk * 65 + bb];
                float a0 = ap[0], a1 = ap[1];
                float w0 = wp[0], w1 = wp[1], w2 = wp[2], w3 = wp[3];
                acc[0][0] = fmaf(w0, a0, acc[0][0]); acc[0][1] = fmaf(w0, a1, acc[0][1]);
                acc[1][0] = fmaf(w1, a0, acc[1][0]); acc[1][1] = fmaf(w1, a1, acc[1][1]);
                acc[2][0] = fmaf(w2, a0, acc[2][0]); acc[2][1] = fmaf(w2, a1, acc[2][1]);
                acc[3][0] = fmaf(w3, a0, acc[3][0]); acc[3][1] = fmaf(w3, a1, acc[3][1]);
            }
        }
        int ob = (t & 7) * 4, bb = (t >> 3) * 2;
        if (mode == 2) {
#pragma unroll
            for (int i = 0; i < 4; ++i)
#pragma unroll
                for (int j = 0; j < 2; ++j)
                    a.out[(size_t)(rb + bb + j) * 256 + o0 + ob + i] =
                        sigmoidf_(acc[i][j] + a.b_out[o0 + ob + i]);
        } else {
#pragma unroll
            for (int i = 0; i < 4; ++i)
#pragma unroll
                for (int j = 0; j < 2; ++j)
                    C[(size_t)(rb + bb + j) * Ncols + o0 + ob + i] = acc[i][j];
        }
    }
}

__device__ float biasHead(const Args& a, int i, int q) {
    if (q < 64)  return a.bk[(i << 6) + q];
    if (q == 64) return a.bbeta[i];
    if (q == 65) return a.bg[i];
    if (q <= 68) return a.bs3[i * 3 + q - 66];
    if (q == 69) return a.bgam[i];
    if (q < 134) return a.be[(i << 6) + q - 70];
    return a.ba[(i << 6) + q - 134];
}

// ---- read-only memory sweep; reconstruct states in registers ----
__device__ void sweep_phase(const Args& a, SMem& sm, int napply, int nsims, int sh0, int sh1,
                            int read_state, int read_head, int read_idx) {
    int t = threadIdx.x, lane = t & 15, grp = t >> 4;
    int base = blockIdx.x * 1024;   // 1024 rows/block, 4 blocks per b
    int b = base >> 12;
    int m4 = lane * 4;
    float4 e1 = ld4(a.eA + (size_t)(1 * 128 + b) * 64 + m4);
    float4 a1 = ld4(a.aA + (size_t)(1 * 128 + b) * 64 + m4);
    float4 e3 = ld4(a.eA + (size_t)(3 * 128 + b) * 64 + m4);
    float4 a3 = ld4(a.aA + (size_t)(3 * 128 + b) * 64 + m4);
    float4 e5 = ld4(a.eA + (size_t)(5 * 128 + b) * 64 + m4);
    float4 a5 = ld4(a.aA + (size_t)(5 * 128 + b) * 64 + m4);
    float4 k0v = make_float4(0.f, 0.f, 0.f, 0.f), k1v = k0v;
    float kn0 = 0.f, kn1 = 0.f;
    if (nsims > 0) { k0v = ld4(a.keys + (size_t)(sh0 * 128 + b) * 64 + m4); kn0 = a.knorm[sh0 * 128 + b]; }
    if (nsims > 1) { k1v = ld4(a.keys + (size_t)(sh1 * 128 + b) * 64 + m4); kn1 = a.knorm[sh1 * 128 + b]; }
    const float* w1p = a.wbuf + (size_t)1 * 128 * 4096;
    const float* w3p = a.wbuf + (size_t)3 * 128 * 4096;
    const float* w5p = a.wbuf + (size_t)5 * 128 * 4096;
    const float* wrp = (read_head >= 0) ? a.wbuf + (size_t)read_head * 128 * 4096 : nullptr;
    float* sim0 = a.sims + (size_t)sh0 * 128 * 4096;
    float* sim1 = a.sims + (size_t)sh1 * 128 * 4096;
    float4 racc = make_float4(0.f, 0.f, 0.f, 0.f);

    auto proc = [&](float4 m, int row) {
        float4 mr = m;
        if (napply >= 1) {
            float w = w1p[row];
            m.x = m.x * (1.f - w * e1.x) + w * a1.x;
            m.y = m.y * (1.f - w * e1.y) + w * a1.y;
            m.z = m.z * (1.f - w * e1.z) + w * a1.z;
            m.w = m.w * (1.f - w * e1.w) + w * a1.w;
            if (read_state == 1) mr = m;
        }
        if (napply >= 2) {
            float w = w3p[row];
            m.x = m.x * (1.f - w * e3.x) + w * a3.x;
            m.y = m.y * (1.f - w * e3.y) + w * a3.y;
            m.z = m.z * (1.f - w * e3.z) + w * a3.z;
            m.w = m.w * (1.f - w * e3.w) + w * a3.w;
            if (read_state == 2) mr = m;
        }
        if (napply >= 3) {
            float w = w5p[row];
            m.x = m.x * (1.f - w * e5.x) + w * a5.x;
            m.y = m.y * (1.f - w * e5.y) + w * a5.y;
            m.z = m.z * (1.f - w * e5.z) + w * a5.z;
            m.w = m.w * (1.f - w * e5.w) + w * a5.w;
            if (read_state == 3) mr = m;
        }
        if (read_head >= 0) {
            float w = wrp[row];
            racc.x = fmaf(w, mr.x, racc.x);
            racc.y = fmaf(w, mr.y, racc.y);
            racc.z = fmaf(w, mr.z, racc.z);
            racc.w = fmaf(w, mr.w, racc.w);
        }
        if (nsims > 0) {
            float d0 = m.x * k0v.x + m.y * k0v.y + m.z * k0v.z + m.w * k0v.w;
            float nn = m.x * m.x + m.y * m.y + m.z * m.z + m.w * m.w;
            float d1 = 0.f;
            if (nsims > 1) d1 = m.x * k1v.x + m.y * k1v.y + m.z * k1v.z + m.w * k1v.w;
#pragma unroll
            for (int off = 8; off >= 1; off >>= 1) {
                d0 += __shfl_xor(d0, off, 16);
                nn += __shfl_xor(nn, off, 16);
                if (nsims > 1) d1 += __shfl_xor(d1, off, 16);
            }
            if (lane == 0) {
                float nm = sqrtf(nn);
                sim0[row] = d0 / (nm * kn0 + EPSF);
                if (nsims > 1) sim1[row] = d1 / (nm * kn1 + EPSF);
            }
        }
    };

    for (int it = 0; it < 64; it += 8) {
        int r0 = base + it * 16 + grp;
        const float* mp = a.memory + (size_t)r0 * 64 + m4;
        float4 m0 = ld4(mp);
        float4 m1 = ld4(mp + 16 * 64);
        float4 m2 = ld4(mp + 32 * 64);
        float4 m3 = ld4(mp + 48 * 64);
        float4 m4_ = ld4(mp + 64 * 64);
        float4 m5 = ld4(mp + 80 * 64);
        float4 m6 = ld4(mp + 96 * 64);
        float4 m7 = ld4(mp + 112 * 64);
        proc(m0, r0);        proc(m1, r0 + 16);  proc(m2, r0 + 32);  proc(m3, r0 + 48);
        proc(m4_, r0 + 64);  proc(m5, r0 + 80);  proc(m6, r0 + 96);  proc(m7, r0 + 112);
    }
    if (read_head >= 0) {
        *(float4*)(&sm.s.part[grp][m4]) = racc;
        __syncthreads();
        if (t < 64) {
            float s = 0.f;
#pragma unroll
            for (int g2 = 0; g2 < 16; ++g2) s += sm.s.part[g2][t];
            atomicAdd(&a.rbuf[(size_t)(read_idx * 128 + b) * 64 + t], s);
        }
    }
}

// ---- softmax(beta*sim) -> interpolate -> shift -> sharpen -> normalize ----
__device__ void weights_phase(const Args& a, SMem& sm, int head0, int nheads) {
    int pair = blockIdx.x;
    if (pair >= nheads * 128) return;
    int h = head0 + (pair >> 7), b = pair & 127;
    int hb = h * 128 + b;
    float beta = a.betaA[hb], g = a.gA[hb], gamma = a.gammaA[hb];
    float s0 = a.sA[hb * 3 + 0], s1 = a.sA[hb * 3 + 1], s2 = a.sA[hb * 3 + 2];
    const float* sim = a.sims + (size_t)hb * 4096;
    const float* pw = a.prev_weights + (size_t)hb * 4096;
    float* wout = a.wbuf + (size_t)hb * 4096;
    int t = threadIdx.x;
    float tv[16];
    float lmax = -3.4e38f;
#pragma unroll
    for (int j = 0; j < 16; ++j) {
        float x = beta * sim[t + 256 * j];
        tv[j] = x;
        lmax = fmaxf(lmax, x);
    }
    sm.w.red[t] = lmax; __syncthreads();
    for (int s = 128; s > 0; s >>= 1) { if (t < s) sm.w.red[t] = fmaxf(sm.w.red[t], sm.w.red[t + s]); __syncthreads(); }
    float Mx = sm.w.red[0]; __syncthreads();
    float lsum = 0.f;
#pragma unroll
    for (int j = 0; j < 16; ++j) { float ex = expf(tv[j] - Mx); tv[j] = ex; lsum += ex; }
    sm.w.red[t] = lsum; __syncthreads();
    for (int s = 128; s > 0; s >>= 1) { if (t < s) sm.w.red[t] += sm.w.red[t + s]; __syncthreads(); }
    float invS = 1.f / sm.w.red[0]; __syncthreads();
#pragma unroll
    for (int j = 0; j < 16; ++j) {
        int n = t + 256 * j;
        sm.w.wg[n] = g * tv[j] * invS + (1.f - g) * pw[n];
    }
    __syncthreads();
    float lsum2 = 0.f;
#pragma unroll
    for (int j = 0; j < 16; ++j) {
        int n = t + 256 * j;
        float wsft = s0 * sm.w.wg[(n + 1) & 4095] + s1 * sm.w.wg[n] + s2 * sm.w.wg[(n - 1) & 4095];
        float wp = exp2f(gamma * log2f(wsft));
        tv[j] = wp;
        lsum2 += wp;
    }
    sm.w.red[t] = lsum2; __syncthreads();
    for (int s = 128; s > 0; s >>= 1) { if (t < s) sm.w.red[t] += sm.w.red[t + s]; __syncthreads(); }
    float inv2 = 1.f / (sm.w.red[0] + EPSF);
#pragma unroll
    for (int j = 0; j < 16; ++j) wout[t + 256 * j] = tv[j] * inv2;
}

// ------------------------------------------------------------------
__global__ __launch_bounds__(THR, 2) void ntm_fused(Args a) {
    __shared__ SMem sm;
    int t = threadIdx.x;

    gemm_phase(a, sm, 0, 1024, 2048, a.gates);
    gridbar(a, 1);
    if (blockIdx.x < 256) {
        int idx = blockIdx.x * THR + t;
        int j = idx & 511;
        const float* gr = a.gates + (size_t)(idx >> 9) * 2048;
        float gi = gr[j]        + a.b_ih[j]        + a.b_hh[j];
        float gf = gr[512 + j]  + a.b_ih[512 + j]  + a.b_hh[512 + j];
        float gg = gr[1024 + j] + a.b_ih[1024 + j] + a.b_hh[1024 + j];
        float go = gr[1536 + j] + a.b_ih[1536 + j] + a.b_hh[1536 + j];
        float cc = sigmoidf_(gf) * a.c_prev[idx] + sigmoidf_(gi) * tanhf(gg);
        a.cbuf[idx] = cc;
        a.hbuf[idx] = sigmoidf_(go) * tanhf(cc);
    }
    gridbar(a, 2);
    gemm_phase(a, sm, 1, 512, 1600, a.Chead);
    gridbar(a, 3);
    for (int ii = 0; ii < 2; ++ii) {
        int item = blockIdx.x * 2 + ii;
        int i = item >> 7, b = item & 127;
        float val = 0.f;
        if (t < 198) val = a.Chead[(size_t)b * 1600 + i * 198 + t] + biasHead(a, i, t);
        if (t < 64) { a.keys[(size_t)(i * 128 + b) * 64 + t] = val; sm.h.sk[t] = val * val; }
        if (t >= 66 && t <= 68) sm.h.s3[t - 66] = val;
        __syncthreads();
        if (t == 0) {
            float s = 0.f;
            for (int m2 = 0; m2 < 64; ++m2) s += sm.h.sk[m2];
            a.knorm[i * 128 + b] = sqrtf(s);
        }
        if (t == 64) a.betaA[i * 128 + b] = softplusf_(val);
        if (t == 65) a.gA[i * 128 + b] = sigmoidf_(val);
        if (t == 69) a.gammaA[i * 128 + b] = 1.f + softplusf_(val);
        if (t == 66) {
            float mx = fmaxf(sm.h.s3[0], fmaxf(sm.h.s3[1], sm.h.s3[2]));
            float e0 = expf(sm.h.s3[0] - mx), e1 = expf(sm.h.s3[1] - mx), e2 = expf(sm.h.s3[2] - mx);
            float inv = 1.f / (e0 + e1 + e2);
            a.sA[(i * 128 + b) * 3 + 0] = e0 * inv;
            a.sA[(i * 128 + b) * 3 + 1] = e1 * inv;
            a.sA[(i * 128 + b) * 3 + 2] = e2 * inv;
        }
        if (t >= 70 && t < 134)  a.eA[(size_t)(i * 128 + b) * 64 + (t - 70)] = sigmoidf_(val);
        if (t >= 134 && t < 198) a.aA[(size_t)(i * 128 + b) * 64 + (t - 134)] = tanhf(val);
        __syncthreads();
    }
    gridbar(a, 4);
    sweep_phase(a, sm, 0, 2, 0, 1, -1, -1, 0);   gridbar(a, 5);
    weights_phase(a, sm, 0, 2);                  gridbar(a, 6);
    sweep_phase(a, sm, 1, 2, 2, 3, 0, 0, 0);     gridbar(a, 7);
    weights_phase(a, sm, 2, 2);                  gridbar(a, 8);
    sweep_phase(a, sm, 2, 2, 4, 5, 1, 2, 1);     gridbar(a, 9);
    weights_phase(a, sm, 4, 2);                  gridbar(a, 10);
    sweep_phase(a, sm, 3, 1, 6, 6, 2, 4, 2);     gridbar(a, 11);
    weights_phase(a, sm, 6, 1);                  gridbar(a, 12);
    sweep_phase(a, sm, 3, 0, 0, 0, 3, 6, 3);     gridbar(a, 13);
    gemm_phase(a, sm, 2, 768, 256, nullptr);
}

// ------------------------------------------------------------------
extern "C" void kernel_launch(void* const* d_in, const int* in_sizes, int n_in,
                              void* d_out, int out_size, void* d_ws, size_t ws_size,
                              hipStream_t stream) {
    Args a;
    a.in_data      = (const float*)d_in[0];
    a.memory       = (const float*)d_in[1];
    a.h_prev       = (const float*)d_in[2];
    a.c_prev       = (const float*)d_in[3];
    a.prev_reads   = (const float*)d_in[4];
    a.prev_weights = (const float*)d_in[5];
    a.W_ih  = (const float*)d_in[6];
    a.b_ih  = (const float*)d_in[7];
    a.W_hh  = (const float*)d_in[8];
    a.b_hh  = (const float*)d_in[9];
    a.W_out = (const float*)d_in[10];
    a.b_out = (const float*)d_in[11];
    a.Wk    = (const float*)d_in[12];
    a.bk    = (const float*)d_in[13];
    a.Wbeta = (const float*)d_in[14];
    a.bbeta = (const float*)d_in[15];
    a.Wg    = (const float*)d_in[16];
    a.bg    = (const float*)d_in[17];
    a.Ws3   = (const float*)d_in[18];
    a.bs3   = (const float*)d_in[19];
    a.Wgam  = (const float*)d_in[20];
    a.bgam  = (const float*)d_in[21];
    a.We    = (const float*)d_in[22];
    a.be    = (const float*)d_in[23];
    a.Wa    = (const float*)d_in[24];
    a.ba    = (const float*)d_in[25];

    float* ws = (float*)d_ws;
    a.bar_g = (int*)ws;
    a.bar_r = (int*)ws + 1024;
    a.bar_s = (int*)ws + 1088;
    a.rbuf  = ws + 2048;
    size_t off = 2048 + 32768;
    a.gates  = ws + off; off += 262144;
    a.cbuf   = ws + off; off += 65536;
    a.hbuf   = ws + off; off += 65536;
    a.Chead  = ws + off; off += 204800;
    a.keys   = ws + off; off += 65536;
    a.knorm  = ws + off; off += 1024;
    a.betaA  = ws + off; off += 1024;
    a.gA     = ws + off; off += 1024;
    a.gammaA = ws + off; off += 1024;
    a.sA     = ws + off; off += 3072;
    a.eA     = ws + off; off += 65536;
    a.aA     = ws + off; off += 65536;
    a.sims   = ws + off; off += 4194304;
    a.wbuf   = ws + off; off += 4194304;
    a.out    = (float*)d_out;

    hipMemsetAsync(d_ws, 0, (2048 + 32768) * sizeof(float), stream);
    ntm_fused<<<NBLK, THR, 0, stream>>>(a);

    (void)in_sizes; (void)n_in; (void)out_size; (void)ws_size;
}